// Round 1
// baseline (458.387 us; speedup 1.0000x reference)
//
#include <hip/hip_runtime.h>

// SNN forward, round 7. Round-6 analysis: bin_edges2 (166us) was neither
// BW- nor VALU-bound -- it is structural cost (2 passes over 20M edges,
// slot atomics with return, 33MB pair spill) feeding accum_bucket (another
// 4.1M LDS atomics) and a 33MB partial reduce. The scatter target hid_in is
// only 1.6MB (L2-resident) and mask-filtering leaves ~4.4M atomics over
// 400K addresses (~11/addr, negligible contention, fire-and-forget).
// Fix: single-pass masked direct scatter with global atomicAdd; bin/accum/
// partial-reduce phases deleted. Output spikes are binary so atomic
// ordering nondeterminism cannot flip results.

#define N_SENS 10000
#define N_HID  400000
#define N_MOT  1000

#define SENS_MW   320                   // sens mask words (u32) = 10240 bits
#define HID_MW    12512                 // hid mask words (u32) = 400384 bits

#define SC_B      1024
#define SC_EPT    16                    // edges per thread

#define NB_HM     64

// --- masks for sensory (LIF on the fly) and hidden_prev (0/1 floats) -----
__global__ void make_masks(const float* __restrict__ sens_in,
                           const float* __restrict__ sens_mem,
                           const float* __restrict__ hid_prev,
                           uint2* __restrict__ smask,
                           uint2* __restrict__ hmask, int nb_sens) {
    bool pred = false;
    int i;
    uint2* dst;
    int maxw;
    if ((int)blockIdx.x < nb_sens) {
        i = blockIdx.x * blockDim.x + threadIdx.x;
        if (i < N_SENS) pred = (0.9f * sens_mem[i] + 5.0f * sens_in[i]) > 1.0f;
        dst = smask; maxw = SENS_MW / 2;
    } else {
        i = (blockIdx.x - nb_sens) * blockDim.x + threadIdx.x;
        if (i < N_HID) pred = (hid_prev[i] != 0.0f);
        dst = hmask; maxw = HID_MW / 2;
    }
    unsigned long long b = __ballot(pred);
    if ((threadIdx.x & 63) == 0) {
        int w = i >> 6;
        if (w < maxw) dst[w] = make_uint2((unsigned)b, (unsigned)(b >> 32));
    }
}

// --- single-pass masked direct scatter: hid_in[post] += scale*w ----------
// sh blocks first (mask 1.25KB), hh blocks after (mask 50KB). 2 blocks/CU
// (thread cap), ~20 VGPR, atomics are fire-and-forget (no dependent chain).
__global__ __launch_bounds__(SC_B, 8)
void scatter_edges(const int* __restrict__ sh_pre, const int* __restrict__ sh_post,
                   const float* __restrict__ w_sh, const unsigned* __restrict__ smask,
                   int e_sh, int nb_sh,
                   const int* __restrict__ hh_pre, const int* __restrict__ hh_post,
                   const float* __restrict__ w_hh, const unsigned* __restrict__ hmask,
                   int e_hh,
                   float* __restrict__ hid_in) {
    __shared__ unsigned sm[HID_MW];
    const int *pre, *post;
    const float* w;
    const unsigned* gm;
    int mw, n_e, blockStart;
    float scale;
    if ((int)blockIdx.x < nb_sh) {
        pre = sh_pre; post = sh_post; w = w_sh; gm = smask;
        mw = SENS_MW; n_e = e_sh; scale = 1.0f;
        blockStart = blockIdx.x * (SC_B * SC_EPT);
    } else {
        pre = hh_pre; post = hh_post; w = w_hh; gm = hmask;
        mw = HID_MW; n_e = e_hh; scale = 0.5f;
        blockStart = (blockIdx.x - nb_sh) * (SC_B * SC_EPT);
    }
    for (int i = threadIdx.x; i < mw; i += SC_B) sm[i] = gm[i];
    __syncthreads();

    #pragma unroll 4
    for (int j = 0; j < SC_EPT; ++j) {
        int e = blockStart + j * SC_B + threadIdx.x;
        if (e < n_e) {
            int pr = pre[e];
            if ((sm[pr >> 5] >> (pr & 31)) & 1u)
                atomicAdd(&hid_in[post[e]], scale * w[e]);
        }
    }
}

// --- hidden LIF direct from hid_in; emits spike bitmask ------------------
__global__ void lif_hidden_mask(const float* __restrict__ hid_in,
                                const float* __restrict__ mem,
                                uint2* __restrict__ mask) {
    int i = blockIdx.x * blockDim.x + threadIdx.x;
    bool pred = false;
    if (i < N_HID)
        pred = (0.9f * mem[i] + 5.0f * hid_in[i]) > 1.0f;
    unsigned long long bal = __ballot(pred);
    if ((threadIdx.x & 63) == 0) {
        int w = i >> 6;
        if (w < HID_MW / 2)
            mask[w] = make_uint2((unsigned)bal, (unsigned)(bal >> 32));
    }
}

// --- motor: LDS accumulator + LDS hid bitmask, per-block partials --------
__global__ __launch_bounds__(1024, 8)
void scatter_motor_mask(const int* __restrict__ pre,
                        const int* __restrict__ post,
                        const float* __restrict__ w,
                        const unsigned* __restrict__ gmask,
                        float* __restrict__ partials, int n_edges) {
    __shared__ float acc[N_MOT];
    __shared__ unsigned sm[HID_MW];
    for (int i = threadIdx.x; i < HID_MW; i += blockDim.x) sm[i] = gmask[i];
    for (int j = threadIdx.x; j < N_MOT; j += blockDim.x) acc[j] = 0.0f;
    __syncthreads();
    for (int e = blockIdx.x * blockDim.x + threadIdx.x; e < n_edges;
         e += gridDim.x * blockDim.x) {
        int pr = pre[e];
        if ((sm[pr >> 5] >> (pr & 31)) & 1u)
            atomicAdd(&acc[post[e]], w[e]);
    }
    __syncthreads();
    float* out = partials + (size_t)blockIdx.x * N_MOT;
    for (int j = threadIdx.x; j < N_MOT; j += blockDim.x) out[j] = acc[j];
}

__global__ void reduce_lif_motor(const float* __restrict__ partials, int nb,
                                 const float* __restrict__ mem,
                                 float* __restrict__ out) {
    int m = blockIdx.x * blockDim.x + threadIdx.x;
    if (m >= N_MOT) return;
    float sum = 0.0f;
    for (int b = 0; b < nb; ++b) sum += partials[(size_t)b * N_MOT + m];
    float v = 0.9f * mem[m] + 20.0f * sum;
    out[m] = (v > 1.0f) ? 1.0f : 0.0f;
}

// --- fallback (tiny workspace): device-atomic scatter --------------------
__global__ void lif_kernel(const float* __restrict__ inp,
                           const float* __restrict__ mem_in,
                           float* __restrict__ spk,
                           float scale, int n) {
    int i = blockIdx.x * blockDim.x + threadIdx.x;
    if (i < n) {
        float m = 0.9f * mem_in[i] + scale * inp[i];
        spk[i] = (m > 1.0f) ? 1.0f : 0.0f;
    }
}

__global__ void scatter_dev(const int* __restrict__ pre,
                            const int* __restrict__ post,
                            const float* __restrict__ w,
                            const float* __restrict__ spikes,
                            float* __restrict__ out,
                            float scale, int n_edges) {
    int e = blockIdx.x * blockDim.x + threadIdx.x;
    if (e >= n_edges) return;
    float s = spikes[pre[e]];
    if (s != 0.0f) atomicAdd(&out[post[e]], scale * w[e] * s);
}

__global__ void lif_hidden_direct(const float* __restrict__ hid_in,
                                  const float* __restrict__ mem,
                                  float* __restrict__ spk) {
    int i = blockIdx.x * blockDim.x + threadIdx.x;
    if (i >= N_HID) return;
    float m = 0.9f * mem[i] + 5.0f * hid_in[i];
    spk[i] = (m > 1.0f) ? 1.0f : 0.0f;
}

__global__ void scatter_motor_f(const int* __restrict__ pre,
                                const int* __restrict__ post,
                                const float* __restrict__ w,
                                const float* __restrict__ spikes,
                                float* __restrict__ partials, int n_edges) {
    __shared__ float acc[N_MOT];
    for (int j = threadIdx.x; j < N_MOT; j += blockDim.x) acc[j] = 0.0f;
    __syncthreads();
    for (int e = blockIdx.x * blockDim.x + threadIdx.x; e < n_edges;
         e += gridDim.x * blockDim.x) {
        float s = spikes[pre[e]];
        if (s != 0.0f) atomicAdd(&acc[post[e]], w[e] * s);
    }
    __syncthreads();
    float* out = partials + (size_t)blockIdx.x * N_MOT;
    for (int j = threadIdx.x; j < N_MOT; j += blockDim.x) out[j] = acc[j];
}

extern "C" void kernel_launch(void* const* d_in, const int* in_sizes, int n_in,
                              void* d_out, int out_size, void* d_ws, size_t ws_size,
                              hipStream_t stream) {
    const float* sensory_input = (const float*)d_in[0];
    const float* sensory_mem   = (const float*)d_in[1];
    const float* hidden_mem    = (const float*)d_in[2];
    const float* motor_mem     = (const float*)d_in[3];
    const float* hidden_prev   = (const float*)d_in[4];
    const float* w_sh          = (const float*)d_in[5];
    const float* w_hh          = (const float*)d_in[6];
    const float* w_hm          = (const float*)d_in[7];
    const int*   sh_pre        = (const int*)d_in[8];
    const int*   sh_post       = (const int*)d_in[9];
    const int*   hh_pre        = (const int*)d_in[10];
    const int*   hh_post       = (const int*)d_in[11];
    const int*   hm_pre        = (const int*)d_in[12];
    const int*   hm_post       = (const int*)d_in[13];
    const int e_sh = in_sizes[5];
    const int e_hh = in_sizes[6];
    const int e_hm = in_sizes[7];
    const int B = 256;

    // fast ws layout (floats, offsets even -> uint2-aligned):
    size_t o_hid    = 0;                                // N_HID
    size_t o_smask  = o_hid + N_HID;                    // SENS_MW
    size_t o_hmaskp = o_smask + SENS_MW;                // HID_MW
    size_t o_hmasks = o_hmaskp + HID_MW;                // HID_MW
    size_t o_mpart  = o_hmasks + HID_MW;                // NB_HM*N_MOT
    size_t f_need   = o_mpart + (size_t)NB_HM * N_MOT;
    bool fast = (ws_size / sizeof(float)) >= f_need;

    float* ws = (float*)d_ws;
    if (fast) {
        float*    hid_in = ws + o_hid;
        unsigned* smask  = (unsigned*)(ws + o_smask);
        unsigned* hmaskp = (unsigned*)(ws + o_hmaskp);
        unsigned* hmasks = (unsigned*)(ws + o_hmasks);
        float*    mpart  = ws + o_mpart;

        hipMemsetAsync(hid_in, 0, (size_t)N_HID * sizeof(float), stream);

        int nb_sens = (N_SENS + B - 1) / B;                      // 40
        int nb_hidm = (N_HID + B - 1) / B;                       // 1563
        make_masks<<<nb_sens + nb_hidm, B, 0, stream>>>(
            sensory_input, sensory_mem, hidden_prev,
            (uint2*)smask, (uint2*)hmaskp, nb_sens);

        int nb_sh = (e_sh + SC_B * SC_EPT - 1) / (SC_B * SC_EPT);  // 245
        int nb_hh = (e_hh + SC_B * SC_EPT - 1) / (SC_B * SC_EPT);  // 977
        scatter_edges<<<nb_sh + nb_hh, SC_B, 0, stream>>>(
            sh_pre, sh_post, w_sh, smask, e_sh, nb_sh,
            hh_pre, hh_post, w_hh, hmaskp, e_hh, hid_in);

        lif_hidden_mask<<<(N_HID + B - 1) / B, B, 0, stream>>>(
            hid_in, hidden_mem, (uint2*)hmasks);
        scatter_motor_mask<<<NB_HM, 1024, 0, stream>>>(
            hm_pre, hm_post, w_hm, hmasks, mpart, e_hm);
        reduce_lif_motor<<<(N_MOT + B - 1) / B, B, 0, stream>>>(
            mpart, NB_HM, motor_mem, (float*)d_out);
    } else {
        float* hid_in   = ws;
        float* sens_spk = hid_in + N_HID;
        float* hid_spk  = sens_spk + 10016;
        float* mpart    = hid_spk + N_HID;
        hipMemsetAsync(hid_in, 0, (size_t)N_HID * sizeof(float), stream);
        lif_kernel<<<(N_SENS + B - 1) / B, B, 0, stream>>>(
            sensory_input, sensory_mem, sens_spk, 5.0f, N_SENS);
        scatter_dev<<<(e_sh + B - 1) / B, B, 0, stream>>>(
            sh_pre, sh_post, w_sh, sens_spk, hid_in, 1.0f, e_sh);
        scatter_dev<<<(e_hh + B - 1) / B, B, 0, stream>>>(
            hh_pre, hh_post, w_hh, hidden_prev, hid_in, 0.5f, e_hh);
        lif_hidden_direct<<<(N_HID + B - 1) / B, B, 0, stream>>>(
            hid_in, hidden_mem, hid_spk);
        scatter_motor_f<<<NB_HM, B, 0, stream>>>(
            hm_pre, hm_post, w_hm, hid_spk, mpart, e_hm);
        reduce_lif_motor<<<(N_MOT + B - 1) / B, B, 0, stream>>>(
            mpart, NB_HM, motor_mem, (float*)d_out);
    }
}

// Round 2
// 347.786 us; speedup vs baseline: 1.3180x; 1.3180x over previous
//
#include <hip/hip_runtime.h>

// SNN forward, round 8. Round-7 lesson: device fp32 atomics execute at the
// memory-side coherence point (WRITE_SIZE 135MB for a 1.6MB target, ~17G
// atomics/s) -- direct scatter is atomic-rate-bound. Revert to bin->LDS-accum,
// but fix round-6 bin's real costs: it streamed 20M edges TWICE and ran two
// per-edge LDS-atomic-with-return storms. New bin: single global pass,
// wave-ballot compaction into an LDS pair buffer (1 LDS atomic per wave-iter),
// 4-way-replicated LDS histogram, ONE global cursor atomic per bucket per
// block, bucket-grouped flush. hh loads post/w only for ~5% active edges.
// Overflow (LDS buf or CAP) falls back to device atomics into a zeroed
// 'extra' array folded into the LIF reduce (correct for any input).

#define N_SENS 10000
#define N_HID  400000
#define N_MOT  1000

#define CHUNK_LOG 14
#define CHUNK     (1 << CHUNK_LOG)      // 16384 floats = 64 KB LDS chunk
#define NBUCKET   25                    // ceil(400000 / 16384)
#define CAP       204800                // pairs/bucket (expect ~178K max)
#define NCOPY     10                    // accum blocks per bucket (250 total)

#define SENS_MW   320                   // sens mask words (u32) = 10240 bits
#define HID_MW    12512                 // hid mask words (u32) = 400384 bits

#define BUF_SH    4096                  // = 1024*EPT_SH -> cannot overflow
#define BUF_HH    2048                  // ~2.5x expected actives (819)
#define EPT_SH    4
#define EPT_HH    16

#define NB_HM     64

// --- masks for sensory (LIF on the fly) and hidden_prev (0/1 floats) -----
__global__ void make_masks(const float* __restrict__ sens_in,
                           const float* __restrict__ sens_mem,
                           const float* __restrict__ hid_prev,
                           uint2* __restrict__ smask,
                           uint2* __restrict__ hmask, int nb_sens) {
    bool pred = false;
    int i;
    uint2* dst;
    int maxw;
    if ((int)blockIdx.x < nb_sens) {
        i = blockIdx.x * blockDim.x + threadIdx.x;
        if (i < N_SENS) pred = (0.9f * sens_mem[i] + 5.0f * sens_in[i]) > 1.0f;
        dst = smask; maxw = SENS_MW / 2;
    } else {
        i = (blockIdx.x - nb_sens) * blockDim.x + threadIdx.x;
        if (i < N_HID) pred = (hid_prev[i] != 0.0f);
        dst = hmask; maxw = HID_MW / 2;
    }
    unsigned long long b = __ballot(pred);
    if ((threadIdx.x & 63) == 0) {
        int w = i >> 6;
        if (w < maxw) dst[w] = make_uint2((unsigned)b, (unsigned)(b >> 32));
    }
}

// --- single-pass bin: ballot-compact actives to LDS, then bucket-flush ---
template <int MW, int BUFCAP, int EPT>
__global__ __launch_bounds__(1024, 8)
void bin_onepass(const int* __restrict__ pre, const int* __restrict__ post,
                 const float* __restrict__ w, const unsigned* __restrict__ gmask,
                 int n_e, float scale,
                 uint2* __restrict__ pairs, int* __restrict__ gcursor,
                 float* __restrict__ extra) {
    __shared__ unsigned sm[MW];
    __shared__ uint2 buf[BUFCAP];
    __shared__ int h[4][32];
    __shared__ int gb[32];
    __shared__ int lcur[32];
    __shared__ int total;

    const int tid = threadIdx.x;
    const int lane = tid & 63;
    for (int i = tid; i < MW; i += 1024) sm[i] = gmask[i];
    if (tid < 128) ((int*)h)[tid] = 0;
    if (tid == 0) total = 0;
    __syncthreads();

    int blockStart = blockIdx.x * (1024 * EPT);
    #pragma unroll
    for (int j = 0; j < EPT; ++j) {
        int e = blockStart + j * 1024 + tid;
        bool act = false;
        unsigned p = 0; float wv = 0.0f;
        if (e < n_e) {
            int pr = pre[e];
            act = (sm[pr >> 5] >> (pr & 31)) & 1u;
            if (act) { p = (unsigned)post[e]; wv = scale * w[e]; }
        }
        unsigned long long m = __ballot(act);
        if (m) {
            int rank = __popcll(m & ((1ull << lane) - 1ull));
            int base = 0;
            if (lane == 0) base = atomicAdd(&total, __popcll(m));
            base = __shfl(base, 0);
            if (act) {
                int k = base + rank;
                if (k < BUFCAP) buf[k] = make_uint2(p, __float_as_uint(wv));
                else atomicAdd(&extra[p], wv);   // ~never taken
            }
        }
    }
    __syncthreads();
    int tot = total; if (tot > BUFCAP) tot = BUFCAP;

    // in-LDS histogram (4-way replicated counters)
    int rep = (tid >> 6) & 3;
    for (int k = tid; k < tot; k += 1024)
        atomicAdd(&h[rep][buf[k].x >> CHUNK_LOG], 1);
    __syncthreads();
    if (tid < NBUCKET) {
        int hb = h[0][tid] + h[1][tid] + h[2][tid] + h[3][tid];
        gb[tid] = hb ? atomicAdd(&gcursor[tid], hb) : 0;
        lcur[tid] = 0;
    }
    __syncthreads();

    // flush: bucket-grouped global writes
    for (int k = tid; k < tot; k += 1024) {
        uint2 u = buf[k];
        int b = u.x >> CHUNK_LOG;
        int s = atomicAdd(&lcur[b], 1);
        int pos = gb[b] + s;
        if (pos < CAP)
            pairs[(size_t)b * CAP + pos] =
                make_uint2(u.x & (CHUNK - 1), u.y);
        else
            atomicAdd(&extra[u.x], __uint_as_float(u.y));  // ~never taken
    }
}

// --- Phase B: LDS ds_add accumulation per (bucket, copy) -----------------
__global__ __launch_bounds__(1024, 8)
void accum_bucket(const uint2* __restrict__ pairs,
                  const int* __restrict__ cursors,
                  float* __restrict__ partials) {
    int bucket = blockIdx.x / NCOPY;
    int copy   = blockIdx.x % NCOPY;
    __shared__ float acc[CHUNK];
    for (int i = threadIdx.x; i < CHUNK; i += blockDim.x) acc[i] = 0.0f;
    __syncthreads();

    int count = cursors[bucket];
    if (count > CAP) count = CAP;
    int begin = (int)((long long)count * copy / NCOPY);
    int end   = (int)((long long)count * (copy + 1) / NCOPY);
    const uint2* src = pairs + (size_t)bucket * CAP;
    for (int i = begin + threadIdx.x; i < end; i += blockDim.x) {
        uint2 u = src[i];
        atomicAdd(&acc[u.x], __uint_as_float(u.y));           // LDS atomic
    }
    __syncthreads();
    float* dst = partials + ((size_t)bucket * NCOPY + copy) * CHUNK;
    for (int i = threadIdx.x; i < CHUNK; i += blockDim.x) dst[i] = acc[i];
}

// --- hidden LIF fused with partial merge (+overflow); emits bitmask ------
__global__ void reduce_lif_hidden_mask(const float* __restrict__ partials,
                                       const float* __restrict__ extra,
                                       const float* __restrict__ mem,
                                       uint2* __restrict__ mask) {
    int i = blockIdx.x * blockDim.x + threadIdx.x;
    bool pred = false;
    if (i < N_HID) {
        int b = i >> CHUNK_LOG, local = i & (CHUNK - 1);
        const float* p = partials + (size_t)b * NCOPY * CHUNK + local;
        float sum = extra[i];
        #pragma unroll
        for (int c = 0; c < NCOPY; ++c) sum += p[(size_t)c * CHUNK];
        pred = (0.9f * mem[i] + 5.0f * sum) > 1.0f;
    }
    unsigned long long bal = __ballot(pred);
    if ((threadIdx.x & 63) == 0) {
        int w = i >> 6;
        if (w < HID_MW / 2)
            mask[w] = make_uint2((unsigned)bal, (unsigned)(bal >> 32));
    }
}

// --- motor: LDS accumulator + LDS hid bitmask, per-block partials --------
__global__ __launch_bounds__(1024, 8)
void scatter_motor_mask(const int* __restrict__ pre,
                        const int* __restrict__ post,
                        const float* __restrict__ w,
                        const unsigned* __restrict__ gmask,
                        float* __restrict__ partials, int n_edges) {
    __shared__ float acc[N_MOT];
    __shared__ unsigned sm[HID_MW];
    for (int i = threadIdx.x; i < HID_MW; i += blockDim.x) sm[i] = gmask[i];
    for (int j = threadIdx.x; j < N_MOT; j += blockDim.x) acc[j] = 0.0f;
    __syncthreads();
    for (int e = blockIdx.x * blockDim.x + threadIdx.x; e < n_edges;
         e += gridDim.x * blockDim.x) {
        int pr = pre[e];
        if ((sm[pr >> 5] >> (pr & 31)) & 1u)
            atomicAdd(&acc[post[e]], w[e]);
    }
    __syncthreads();
    float* out = partials + (size_t)blockIdx.x * N_MOT;
    for (int j = threadIdx.x; j < N_MOT; j += blockDim.x) out[j] = acc[j];
}

__global__ void reduce_lif_motor(const float* __restrict__ partials, int nb,
                                 const float* __restrict__ mem,
                                 float* __restrict__ out) {
    int m = blockIdx.x * blockDim.x + threadIdx.x;
    if (m >= N_MOT) return;
    float sum = 0.0f;
    for (int b = 0; b < nb; ++b) sum += partials[(size_t)b * N_MOT + m];
    float v = 0.9f * mem[m] + 20.0f * sum;
    out[m] = (v > 1.0f) ? 1.0f : 0.0f;
}

// --- fallback (tiny workspace): device-atomic scatter --------------------
__global__ void lif_kernel(const float* __restrict__ inp,
                           const float* __restrict__ mem_in,
                           float* __restrict__ spk,
                           float scale, int n) {
    int i = blockIdx.x * blockDim.x + threadIdx.x;
    if (i < n) {
        float m = 0.9f * mem_in[i] + scale * inp[i];
        spk[i] = (m > 1.0f) ? 1.0f : 0.0f;
    }
}

__global__ void scatter_dev(const int* __restrict__ pre,
                            const int* __restrict__ post,
                            const float* __restrict__ w,
                            const float* __restrict__ spikes,
                            float* __restrict__ out,
                            float scale, int n_edges) {
    int e = blockIdx.x * blockDim.x + threadIdx.x;
    if (e >= n_edges) return;
    float s = spikes[pre[e]];
    if (s != 0.0f) atomicAdd(&out[post[e]], scale * w[e] * s);
}

__global__ void lif_hidden_direct(const float* __restrict__ hid_in,
                                  const float* __restrict__ mem,
                                  float* __restrict__ spk) {
    int i = blockIdx.x * blockDim.x + threadIdx.x;
    if (i >= N_HID) return;
    float m = 0.9f * mem[i] + 5.0f * hid_in[i];
    spk[i] = (m > 1.0f) ? 1.0f : 0.0f;
}

__global__ void scatter_motor_f(const int* __restrict__ pre,
                                const int* __restrict__ post,
                                const float* __restrict__ w,
                                const float* __restrict__ spikes,
                                float* __restrict__ partials, int n_edges) {
    __shared__ float acc[N_MOT];
    for (int j = threadIdx.x; j < N_MOT; j += blockDim.x) acc[j] = 0.0f;
    __syncthreads();
    for (int e = blockIdx.x * blockDim.x + threadIdx.x; e < n_edges;
         e += gridDim.x * blockDim.x) {
        float s = spikes[pre[e]];
        if (s != 0.0f) atomicAdd(&acc[post[e]], w[e] * s);
    }
    __syncthreads();
    float* out = partials + (size_t)blockIdx.x * N_MOT;
    for (int j = threadIdx.x; j < N_MOT; j += blockDim.x) out[j] = acc[j];
}

extern "C" void kernel_launch(void* const* d_in, const int* in_sizes, int n_in,
                              void* d_out, int out_size, void* d_ws, size_t ws_size,
                              hipStream_t stream) {
    const float* sensory_input = (const float*)d_in[0];
    const float* sensory_mem   = (const float*)d_in[1];
    const float* hidden_mem    = (const float*)d_in[2];
    const float* motor_mem     = (const float*)d_in[3];
    const float* hidden_prev   = (const float*)d_in[4];
    const float* w_sh          = (const float*)d_in[5];
    const float* w_hh          = (const float*)d_in[6];
    const float* w_hm          = (const float*)d_in[7];
    const int*   sh_pre        = (const int*)d_in[8];
    const int*   sh_post       = (const int*)d_in[9];
    const int*   hh_pre        = (const int*)d_in[10];
    const int*   hh_post       = (const int*)d_in[11];
    const int*   hm_pre        = (const int*)d_in[12];
    const int*   hm_post       = (const int*)d_in[13];
    const int e_sh = in_sizes[5];
    const int e_hh = in_sizes[6];
    const int e_hm = in_sizes[7];
    const int B = 256;

    // fast ws layout (floats, offsets even -> uint2-aligned):
    size_t o_cursor = 0;                                 // 32
    size_t o_extra  = 32;                                // N_HID
    size_t o_pairs  = o_extra + N_HID;                   // NBUCKET*CAP*2
    size_t o_part   = o_pairs + (size_t)NBUCKET * CAP * 2;
    size_t o_smask  = o_part + (size_t)NBUCKET * NCOPY * CHUNK;
    size_t o_hmaskp = o_smask + SENS_MW;
    size_t o_hmasks = o_hmaskp + HID_MW;
    size_t o_mpart  = o_hmasks + HID_MW;
    size_t f_need   = o_mpart + (size_t)NB_HM * N_MOT;
    bool fast = (ws_size / sizeof(float)) >= f_need;

    float* ws = (float*)d_ws;
    if (fast) {
        int*      cursors = (int*)(ws + o_cursor);
        float*    extra   = ws + o_extra;
        uint2*    pairs   = (uint2*)(ws + o_pairs);
        float*    part    = ws + o_part;
        unsigned* smask   = (unsigned*)(ws + o_smask);
        unsigned* hmaskp  = (unsigned*)(ws + o_hmaskp);
        unsigned* hmasks  = (unsigned*)(ws + o_hmasks);
        float*    mpart   = ws + o_mpart;

        // zero cursors + overflow accumulator in one call
        hipMemsetAsync(cursors, 0, (32 + N_HID) * sizeof(float), stream);

        int nb_sens = (N_SENS + B - 1) / B;                      // 40
        int nb_hidm = (N_HID + B - 1) / B;                       // 1563
        make_masks<<<nb_sens + nb_hidm, B, 0, stream>>>(
            sensory_input, sensory_mem, hidden_prev,
            (uint2*)smask, (uint2*)hmaskp, nb_sens);

        int nb_sh = (e_sh + 1024 * EPT_SH - 1) / (1024 * EPT_SH);  // 977
        int nb_hh = (e_hh + 1024 * EPT_HH - 1) / (1024 * EPT_HH);  // 977
        bin_onepass<SENS_MW, BUF_SH, EPT_SH><<<nb_sh, 1024, 0, stream>>>(
            sh_pre, sh_post, w_sh, smask, e_sh, 1.0f, pairs, cursors, extra);
        bin_onepass<HID_MW, BUF_HH, EPT_HH><<<nb_hh, 1024, 0, stream>>>(
            hh_pre, hh_post, w_hh, hmaskp, e_hh, 0.5f, pairs, cursors, extra);

        accum_bucket<<<NBUCKET * NCOPY, 1024, 0, stream>>>(pairs, cursors, part);
        reduce_lif_hidden_mask<<<(N_HID + B - 1) / B, B, 0, stream>>>(
            part, extra, hidden_mem, (uint2*)hmasks);
        scatter_motor_mask<<<NB_HM, 1024, 0, stream>>>(
            hm_pre, hm_post, w_hm, hmasks, mpart, e_hm);
        reduce_lif_motor<<<(N_MOT + B - 1) / B, B, 0, stream>>>(
            mpart, NB_HM, motor_mem, (float*)d_out);
    } else {
        float* hid_in   = ws;
        float* sens_spk = hid_in + N_HID;
        float* hid_spk  = sens_spk + 10016;
        float* mpart    = hid_spk + N_HID;
        hipMemsetAsync(hid_in, 0, (size_t)N_HID * sizeof(float), stream);
        lif_kernel<<<(N_SENS + B - 1) / B, B, 0, stream>>>(
            sensory_input, sensory_mem, sens_spk, 5.0f, N_SENS);
        scatter_dev<<<(e_sh + B - 1) / B, B, 0, stream>>>(
            sh_pre, sh_post, w_sh, sens_spk, hid_in, 1.0f, e_sh);
        scatter_dev<<<(e_hh + B - 1) / B, B, 0, stream>>>(
            hh_pre, hh_post, w_hh, hidden_prev, hid_in, 0.5f, e_hh);
        lif_hidden_direct<<<(N_HID + B - 1) / B, B, 0, stream>>>(
            hid_in, hidden_mem, hid_spk);
        scatter_motor_f<<<NB_HM, B, 0, stream>>>(
            hm_pre, hm_post, w_hm, hid_spk, mpart, e_hm);
        reduce_lif_motor<<<(N_MOT + B - 1) / B, B, 0, stream>>>(
            mpart, NB_HM, motor_mem, (float*)d_out);
    }
}